// Round 9
// baseline (264.501 us; speedup 1.0000x reference)
//
#include <hip/hip_runtime.h>
#include <limits.h>
#include <math.h>

typedef unsigned long long u64;
typedef unsigned int u32;
typedef float f32x4 __attribute__((ext_vector_type(4)));
typedef float f32x2 __attribute__((ext_vector_type(2)));

// ---------------------------------------------------------------------------
// Sortable-key top-k: pack (f32 value, index) into one u64 so that plain
// unsigned max (largest-k) / min (smallest-k) implements jax.lax.top_k's
// ordering including the lowest-index-wins tie-break.
//   largest : key = ord(v)<<32 | ~idx   (max; tie -> larger ~idx -> smaller idx)
//   smallest: key = ord(v)<<32 |  idx   (min; tie -> smaller idx)
// Sentinels: 0 for largest, ~0ull for smallest.
// ---------------------------------------------------------------------------
__device__ __forceinline__ u32 f2ord(float v) {
    u32 u = __float_as_uint(v);
    return u ^ (((u32)((int)u >> 31)) | 0x80000000u);
}
__device__ __forceinline__ float ord2f(u32 s) {
    u32 u = (s & 0x80000000u) ? (s & 0x7FFFFFFFu) : ~s;
    return __uint_as_float(u);
}
__device__ __forceinline__ u64 keylg(float v, u32 i) { return ((u64)f2ord(v) << 32) | (u64)(~i); }
__device__ __forceinline__ u64 keysm(float v, u32 i) { return ((u64)f2ord(v) << 32) | (u64)i; }
__device__ __forceinline__ float val_of(u64 k) { return ord2f((u32)(k >> 32)); }
__device__ __forceinline__ float idxf_lg(u64 k) { return (float)(~(u32)k); }
__device__ __forceinline__ float idxf_sm(u64 k) { return (float)((u32)k); }

__device__ __forceinline__ u64 mx64(u64 a, u64 b) { return a > b ? a : b; }
__device__ __forceinline__ u64 mn64(u64 a, u64 b) { return a < b ? a : b; }

// Branchless insert into best-first sorted 3-list (largest).
__device__ __forceinline__ void ins3_lg(u64& s0, u64& s1, u64& s2, u64 k) {
    u64 t0 = mx64(s0, k), r0 = mn64(s0, k);
    u64 t1 = mx64(s1, r0), r1 = mn64(s1, r0);
    s0 = t0; s1 = t1; s2 = mx64(s2, r1);
}

__device__ __forceinline__ void ce_max(u64& a, u64& b) { u64 h = mx64(a, b), l = mn64(a, b); a = h; b = l; }
__device__ __forceinline__ void ce_min(u64& a, u64& b) { u64 l = mn64(a, b), h = mx64(a, b); a = l; b = h; }

// Merge two desc-sorted 2-lists -> best 2 (into A). 4 ops, chain 2.
__device__ __forceinline__ void merge2_lg(u64& a0, u64& a1, u64 b0, u64 b1) {
    u64 l0 = mx64(a0, b1), l1 = mx64(a1, b0);
    a0 = mx64(l0, l1); a1 = mn64(l0, l1);
}
__device__ __forceinline__ void merge3_lg(u64& a0, u64& a1, u64& a2, u64 b0, u64 b1, u64 b2) {
    u64 l0 = mx64(a0, b2), l1 = mx64(a1, b1), l2 = mx64(a2, b0);
    ce_max(l0, l1); ce_max(l1, l2); ce_max(l0, l1);
    a0 = l0; a1 = l1; a2 = l2;
}
// Merge asc-sorted 4-list B into asc state A -> best(smallest) 4. 8 ops.
__device__ __forceinline__ void merge4_sm(u64& a0, u64& a1, u64& a2, u64& a3,
                                          u64 b0, u64 b1, u64 b2, u64 b3) {
    u64 l0 = mn64(a0, b3), l1 = mn64(a1, b2), l2 = mn64(a2, b1), l3 = mn64(a3, b0);
    ce_min(l0, l2); ce_min(l1, l3); ce_min(l0, l1); ce_min(l2, l3);
    a0 = l0; a1 = l1; a2 = l2; a3 = l3;
}

__device__ __forceinline__ u64 shx64(u64 v, int m) {
    u32 hi = __shfl_xor((u32)(v >> 32), m);
    u32 lo = __shfl_xor((u32)v, m);
    return ((u64)hi << 32) | (u64)lo;
}

// Tree top-2 (largest) of 4 values -> desc 2-list (o0 >= o1). chain 3.
__device__ __forceinline__ void top2of4_lg(f32x4 f, u32 b, u64& o0, u64& o1) {
    u64 k0 = keylg(f.x, b), k1 = keylg(f.y, b + 1);
    u64 k2 = keylg(f.z, b + 2), k3 = keylg(f.w, b + 3);
    u64 h0 = mx64(k0, k1), l0 = mn64(k0, k1);
    u64 h1 = mx64(k2, k3), l1 = mn64(k2, k3);
    u64 m0 = mx64(h0, l1), m1 = mx64(l0, h1);
    o0 = mx64(m0, m1); o1 = mn64(m0, m1);
}

// Full asc sort of 4 keys (smallest). 10 ops (2+2 merge network).
__device__ __forceinline__ void sort4_sm(f32x4 f, u32 bse,
                                         u64& b0, u64& b1, u64& b2, u64& b3) {
    u64 k0 = keysm(f.x, bse), k1 = keysm(f.y, bse + 1);
    u64 k2 = keysm(f.z, bse + 2), k3 = keysm(f.w, bse + 3);
    u64 p0 = mn64(k0, k1), p1 = mx64(k0, k1);
    u64 q0 = mn64(k2, k3), q1 = mx64(k2, k3);
    b0 = mn64(p0, q0); u64 t = mx64(p0, q0);
    b3 = mx64(p1, q1); u64 u = mn64(p1, q1);
    b1 = mn64(t, u); b2 = mx64(t, u);
}

#define NTL4(p) __builtin_nontemporal_load((const f32x4*)(p))
#define NTL2(p) __builtin_nontemporal_load((const f32x2*)(p))

// ---------------------------------------------------------------------------
// Single megakernel, LPT order + folded reduction:
//   blocks [0, 1024)     : topk0 — 4 rows/block, 512 KB each (longest)
//   blocks [1024, 1536)  : topk2 phase-1 — ~392 KB each; signals counter
//   blocks [1536, 3584)  : topk1 — 4 rows/block, 64 KB each (tail filler)
//   blocks [3584, 3712)  : topk2 reducers — spin on counter==512 (dispatched
//                          last; p1 is in the first co-residency cohort, so
//                          spin is short and the reduce overlaps the tail)
// ---------------------------------------------------------------------------
__global__ __launch_bounds__(256) void mega_kernel(
    const float* __restrict__ x0, float* __restrict__ o0v, float* __restrict__ o0i,
    const float* __restrict__ x1, float* __restrict__ o1v, float* __restrict__ o1i,
    const float* __restrict__ x2, u64* __restrict__ part, u32* __restrict__ counter,
    float* __restrict__ o2v, float* __restrict__ o2i, int rpb, int do_p1)
{
    const int bid  = blockIdx.x;
    const int wave = threadIdx.x >> 6;
    const int lane = threadIdx.x & 63;

    if (bid < 1024) {
        // ---- topk0: top-2 largest along rows of (4096, 32000), wave/row ----
        // 8 float4 in flight (128 B/lane); dual accumulators A/B.
        const int row = bid * 4 + wave;
        const f32x4* xr = (const f32x4*)(x0 + (size_t)row * 32000);
        u64 sA0 = 0, sA1 = 0, sB0 = 0, sB1 = 0;

        // 8000 float4/row; 125/lane = 15*8 + 5
        int v = lane;
        for (int it = 0; it < 15; ++it, v += 512) {
            f32x4 t0 = NTL4(&xr[v]);
            f32x4 t1 = NTL4(&xr[v + 64]);
            f32x4 t2 = NTL4(&xr[v + 128]);
            f32x4 t3 = NTL4(&xr[v + 192]);
            f32x4 t4 = NTL4(&xr[v + 256]);
            f32x4 t5 = NTL4(&xr[v + 320]);
            f32x4 t6 = NTL4(&xr[v + 384]);
            f32x4 t7 = NTL4(&xr[v + 448]);
            u64 w0, w1;
            top2of4_lg(t0, (u32)(v * 4),         w0, w1); merge2_lg(sA0, sA1, w0, w1);
            top2of4_lg(t1, (u32)((v + 64) * 4),  w0, w1); merge2_lg(sB0, sB1, w0, w1);
            top2of4_lg(t2, (u32)((v + 128) * 4), w0, w1); merge2_lg(sA0, sA1, w0, w1);
            top2of4_lg(t3, (u32)((v + 192) * 4), w0, w1); merge2_lg(sB0, sB1, w0, w1);
            top2of4_lg(t4, (u32)((v + 256) * 4), w0, w1); merge2_lg(sA0, sA1, w0, w1);
            top2of4_lg(t5, (u32)((v + 320) * 4), w0, w1); merge2_lg(sB0, sB1, w0, w1);
            top2of4_lg(t6, (u32)((v + 384) * 4), w0, w1); merge2_lg(sA0, sA1, w0, w1);
            top2of4_lg(t7, (u32)((v + 448) * 4), w0, w1); merge2_lg(sB0, sB1, w0, w1);
        }
        {   // tail: 5 more (v = lane + 7680; max 7999)
            f32x4 t0 = NTL4(&xr[v]);
            f32x4 t1 = NTL4(&xr[v + 64]);
            f32x4 t2 = NTL4(&xr[v + 128]);
            f32x4 t3 = NTL4(&xr[v + 192]);
            f32x4 t4 = NTL4(&xr[v + 256]);
            u64 w0, w1;
            top2of4_lg(t0, (u32)(v * 4),         w0, w1); merge2_lg(sA0, sA1, w0, w1);
            top2of4_lg(t1, (u32)((v + 64) * 4),  w0, w1); merge2_lg(sB0, sB1, w0, w1);
            top2of4_lg(t2, (u32)((v + 128) * 4), w0, w1); merge2_lg(sA0, sA1, w0, w1);
            top2of4_lg(t3, (u32)((v + 192) * 4), w0, w1); merge2_lg(sB0, sB1, w0, w1);
            top2of4_lg(t4, (u32)((v + 256) * 4), w0, w1); merge2_lg(sA0, sA1, w0, w1);
        }
        merge2_lg(sA0, sA1, sB0, sB1);

        for (int m = 1; m < 64; m <<= 1) {
            u64 b0 = shx64(sA0, m), b1 = shx64(sA1, m);
            merge2_lg(sA0, sA1, b0, b1);
        }
        if (lane == 0) {
            o0v[row * 2 + 0] = val_of(sA0);  o0v[row * 2 + 1] = val_of(sA1);
            o0i[row * 2 + 0] = idxf_lg(sA0); o0i[row * 2 + 1] = idxf_lg(sA1);
        }

    } else if (bid < 1536) {
        // ---- topk2 phase 1: column-wise top-3 over rpb rows ----
        // Thread owns 2 columns (float2); 8 rows in flight (64 B/lane).
        if (!do_p1) return;
        const int blk = bid - 1024;
        const int c0  = threadIdx.x * 2;
        int rbeg = blk * rpb;
        int rend = rbeg + rpb; if (rend > 100000) rend = 100000;

        u64 a0 = 0, a1 = 0, a2 = 0;   // col c0
        u64 b0 = 0, b1 = 0, b2 = 0;   // col c0+1

#define P1LOAD(r) NTL2(x2 + (size_t)(r) * 512 + c0)
#define P1UPD(f, rr) \
        ins3_lg(a0, a1, a2, keylg((f).x, (u32)(rr))); \
        ins3_lg(b0, b1, b2, keylg((f).y, (u32)(rr)))

        int r = rbeg;
        for (; r + 7 < rend; r += 8) {
            f32x2 f0 = P1LOAD(r);
            f32x2 f1 = P1LOAD(r + 1);
            f32x2 f2 = P1LOAD(r + 2);
            f32x2 f3 = P1LOAD(r + 3);
            f32x2 f4 = P1LOAD(r + 4);
            f32x2 f5 = P1LOAD(r + 5);
            f32x2 f6 = P1LOAD(r + 6);
            f32x2 f7 = P1LOAD(r + 7);
            P1UPD(f0, r);     P1UPD(f1, r + 1); P1UPD(f2, r + 2); P1UPD(f3, r + 3);
            P1UPD(f4, r + 4); P1UPD(f5, r + 5); P1UPD(f6, r + 6); P1UPD(f7, r + 7);
        }
        for (; r < rend; ++r) {
            f32x2 f0 = P1LOAD(r);
            P1UPD(f0, r);
        }
#undef P1LOAD
#undef P1UPD

        u64* base = part + (size_t)blk * 1536;   // [3][512]
        base[0 * 512 + c0] = a0; base[0 * 512 + c0 + 1] = b0;
        base[1 * 512 + c0] = a1; base[1 * 512 + c0 + 1] = b1;
        base[2 * 512 + c0] = a2; base[2 * 512 + c0 + 1] = b2;

        // publish: make this block's partials device-visible, then signal.
        __threadfence();
        __syncthreads();
        if (threadIdx.x == 0) atomicAdd(counter, 1u);

    } else if (bid < 3584) {
        // ---- topk1: top-4 smallest along rows of (8192, 4096), wave/row ----
        // 8 float4 in flight; sort-4 per float4 then one state merge.
        const int row = (bid - 1536) * 4 + wave;
        const f32x4* xr = (const f32x4*)(x1 + (size_t)row * 4096);
        u64 s0 = ~0ull, s1 = ~0ull, s2 = ~0ull, s3 = ~0ull;

#define K1UPD(f, b) { u64 c0_, c1_, c2_, c3_;                      \
        sort4_sm((f), (u32)(b), c0_, c1_, c2_, c3_);               \
        merge4_sm(s0, s1, s2, s3, c0_, c1_, c2_, c3_); }

        // 1024 float4/row; 16/lane = 2*8
        int v = lane;
        for (int it = 0; it < 2; ++it, v += 512) {
            f32x4 t0 = NTL4(&xr[v]);
            f32x4 t1 = NTL4(&xr[v + 64]);
            f32x4 t2 = NTL4(&xr[v + 128]);
            f32x4 t3 = NTL4(&xr[v + 192]);
            f32x4 t4 = NTL4(&xr[v + 256]);
            f32x4 t5 = NTL4(&xr[v + 320]);
            f32x4 t6 = NTL4(&xr[v + 384]);
            f32x4 t7 = NTL4(&xr[v + 448]);
            K1UPD(t0, v * 4);
            K1UPD(t1, (v + 64) * 4);
            K1UPD(t2, (v + 128) * 4);
            K1UPD(t3, (v + 192) * 4);
            K1UPD(t4, (v + 256) * 4);
            K1UPD(t5, (v + 320) * 4);
            K1UPD(t6, (v + 384) * 4);
            K1UPD(t7, (v + 448) * 4);
        }
#undef K1UPD

        for (int m = 1; m < 64; m <<= 1) {
            u64 b0 = shx64(s0, m), b1 = shx64(s1, m);
            u64 b2 = shx64(s2, m), b3 = shx64(s3, m);
            merge4_sm(s0, s1, s2, s3, b0, b1, b2, b3);
        }
        if (lane == 0) {
            o1v[row * 4 + 0] = val_of(s0);  o1v[row * 4 + 1] = val_of(s1);
            o1v[row * 4 + 2] = val_of(s2);  o1v[row * 4 + 3] = val_of(s3);
            o1i[row * 4 + 0] = idxf_sm(s0); o1i[row * 4 + 1] = idxf_sm(s1);
            o1i[row * 4 + 2] = idxf_sm(s2); o1i[row * 4 + 3] = idxf_sm(s3);
        }

    } else {
        // ---- topk2 reducers: wait for all 512 partials, then merge ----
        if (!do_p1) return;
        if (threadIdx.x == 0) {
            while (__hip_atomic_load(counter, __ATOMIC_ACQUIRE,
                                     __HIP_MEMORY_SCOPE_AGENT) < 512u) {
                __builtin_amdgcn_s_sleep(2);
            }
        }
        __syncthreads();

        const int col = (bid - 3584) * 4 + wave;
        u64 a0 = 0, a1 = 0, a2 = 0;
#pragma unroll
        for (int j = 0; j < 8; ++j) {
            const u64* q = part + (size_t)(lane + 64 * j) * 1536 + col;
            merge3_lg(a0, a1, a2, q[0], q[512], q[1024]);
        }
        for (int m = 1; m < 64; m <<= 1) {
            u64 b0 = shx64(a0, m), b1 = shx64(a1, m), b2 = shx64(a2, m);
            merge3_lg(a0, a1, a2, b0, b1, b2);
        }
        if (lane == 0) {
            o2v[0 * 512 + col] = val_of(a0);
            o2v[1 * 512 + col] = val_of(a1);
            o2v[2 * 512 + col] = val_of(a2);
            o2i[0 * 512 + col] = idxf_lg(a0);
            o2i[1 * 512 + col] = idxf_lg(a1);
            o2i[2 * 512 + col] = idxf_lg(a2);
        }
    }
}

// Fallback if workspace is too small (never expected): thread <-> column,
// coalesced row-major streaming, branchless.
__global__ __launch_bounds__(256) void topk2_direct(
    const float* __restrict__ x, float* __restrict__ outv, float* __restrict__ outi)
{
    const int col = blockIdx.x * 256 + threadIdx.x;
    u64 a0 = 0, a1 = 0, a2 = 0;
    for (int r = 0; r < 100000; ++r) {
        float v = x[(size_t)r * 512 + col];
        ins3_lg(a0, a1, a2, keylg(v, (u32)r));
    }
    outv[0 * 512 + col] = val_of(a0);
    outv[1 * 512 + col] = val_of(a1);
    outv[2 * 512 + col] = val_of(a2);
    outi[0 * 512 + col] = idxf_lg(a0);
    outi[1 * 512 + col] = idxf_lg(a1);
    outi[2 * 512 + col] = idxf_lg(a2);
}

extern "C" void kernel_launch(void* const* d_in, const int* in_sizes, int n_in,
                              void* d_out, int out_size, void* d_ws, size_t ws_size,
                              hipStream_t stream) {
    const float* v0 = (const float*)d_in[0];   // (4096, 32000)
    const float* v1 = (const float*)d_in[1];   // (8, 16, 64, 4096)
    const float* v2 = (const float*)d_in[2];   // (100000, 512)
    float* out = (float*)d_out;

    float* o_v4  = out;                 // (4096, 2) values
    float* o_v5  = out + 8192;          // (4096, 2) indices
    float* o_v7  = out + 16384;         // (8,16,64,4) values
    float* o_v8  = out + 49152;         // (8,16,64,4) indices
    float* o_v10 = out + 81920;         // (3, 512) values
    float* o_v11 = out + 83456;         // (3, 512) indices

    const int NB = 512;                           // phase-1 blocks / partials
    int rpb = (100000 + NB - 1) / NB;             // 196
    size_t part_bytes = (size_t)NB * 3 * 512 * sizeof(u64);   // ~6.3 MB
    size_t need = part_bytes + 64;                // + counter slot

    if (ws_size >= need) {
        u64* part    = (u64*)d_ws;                 // [512][3][512]
        u32* counter = (u32*)((char*)d_ws + part_bytes);
        hipMemsetAsync(counter, 0, sizeof(u32), stream);
        mega_kernel<<<3712, 256, 0, stream>>>(v0, o_v4, o_v5,
                                              v1, o_v7, o_v8,
                                              v2, part, counter,
                                              o_v10, o_v11, rpb, 1);
    } else {
        mega_kernel<<<3584, 256, 0, stream>>>(v0, o_v4, o_v5,
                                              v1, o_v7, o_v8,
                                              v2, (u64*)d_ws, (u32*)d_ws,
                                              o_v10, o_v11, rpb, 0);
        topk2_direct<<<2, 256, 0, stream>>>(v2, o_v10, o_v11);
    }
}

// Round 10
// 154.852 us; speedup vs baseline: 1.7081x; 1.7081x over previous
//
#include <hip/hip_runtime.h>
#include <limits.h>
#include <math.h>

typedef unsigned long long u64;
typedef unsigned int u32;
typedef float f32x4 __attribute__((ext_vector_type(4)));
typedef float f32x2 __attribute__((ext_vector_type(2)));

// ---------------------------------------------------------------------------
// Sortable-key top-k: pack (f32 value, index) into one u64 so that plain
// unsigned max (largest-k) / min (smallest-k) implements jax.lax.top_k's
// ordering including the lowest-index-wins tie-break.
//   largest : key = ord(v)<<32 | ~idx   (max; tie -> larger ~idx -> smaller idx)
//   smallest: key = ord(v)<<32 |  idx   (min; tie -> smaller idx)
// Sentinels: 0 for largest, ~0ull for smallest.
// ---------------------------------------------------------------------------
__device__ __forceinline__ u32 f2ord(float v) {
    u32 u = __float_as_uint(v);
    return u ^ (((u32)((int)u >> 31)) | 0x80000000u);
}
__device__ __forceinline__ float ord2f(u32 s) {
    u32 u = (s & 0x80000000u) ? (s & 0x7FFFFFFFu) : ~s;
    return __uint_as_float(u);
}
__device__ __forceinline__ u64 keylg(float v, u32 i) { return ((u64)f2ord(v) << 32) | (u64)(~i); }
__device__ __forceinline__ u64 keysm(float v, u32 i) { return ((u64)f2ord(v) << 32) | (u64)i; }
__device__ __forceinline__ float val_of(u64 k) { return ord2f((u32)(k >> 32)); }
__device__ __forceinline__ float idxf_lg(u64 k) { return (float)(~(u32)k); }
__device__ __forceinline__ float idxf_sm(u64 k) { return (float)((u32)k); }

__device__ __forceinline__ u64 mx64(u64 a, u64 b) { return a > b ? a : b; }
__device__ __forceinline__ u64 mn64(u64 a, u64 b) { return a < b ? a : b; }

// Branchless insert into best-first sorted 3-list (largest).
__device__ __forceinline__ void ins3_lg(u64& s0, u64& s1, u64& s2, u64 k) {
    u64 t0 = mx64(s0, k), r0 = mn64(s0, k);
    u64 t1 = mx64(s1, r0), r1 = mn64(s1, r0);
    s0 = t0; s1 = t1; s2 = mx64(s2, r1);
}

__device__ __forceinline__ void ce_max(u64& a, u64& b) { u64 h = mx64(a, b), l = mn64(a, b); a = h; b = l; }
__device__ __forceinline__ void ce_min(u64& a, u64& b) { u64 l = mn64(a, b), h = mx64(a, b); a = l; b = h; }

// Merge two desc-sorted 2-lists -> best 2 (into A). 4 ops, chain 2.
__device__ __forceinline__ void merge2_lg(u64& a0, u64& a1, u64 b0, u64 b1) {
    u64 l0 = mx64(a0, b1), l1 = mx64(a1, b0);
    a0 = mx64(l0, l1); a1 = mn64(l0, l1);
}
__device__ __forceinline__ void merge3_lg(u64& a0, u64& a1, u64& a2, u64 b0, u64 b1, u64 b2) {
    u64 l0 = mx64(a0, b2), l1 = mx64(a1, b1), l2 = mx64(a2, b0);
    ce_max(l0, l1); ce_max(l1, l2); ce_max(l0, l1);
    a0 = l0; a1 = l1; a2 = l2;
}
// Merge asc-sorted 4-list B into asc state A -> best(smallest) 4. 8 ops.
__device__ __forceinline__ void merge4_sm(u64& a0, u64& a1, u64& a2, u64& a3,
                                          u64 b0, u64 b1, u64 b2, u64 b3) {
    u64 l0 = mn64(a0, b3), l1 = mn64(a1, b2), l2 = mn64(a2, b1), l3 = mn64(a3, b0);
    ce_min(l0, l2); ce_min(l1, l3); ce_min(l0, l1); ce_min(l2, l3);
    a0 = l0; a1 = l1; a2 = l2; a3 = l3;
}

__device__ __forceinline__ u64 shx64(u64 v, int m) {
    u32 hi = __shfl_xor((u32)(v >> 32), m);
    u32 lo = __shfl_xor((u32)v, m);
    return ((u64)hi << 32) | (u64)lo;
}

// Tree top-2 (largest) of 4 values -> desc 2-list (o0 >= o1). chain 3.
__device__ __forceinline__ void top2of4_lg(f32x4 f, u32 b, u64& o0, u64& o1) {
    u64 k0 = keylg(f.x, b), k1 = keylg(f.y, b + 1);
    u64 k2 = keylg(f.z, b + 2), k3 = keylg(f.w, b + 3);
    u64 h0 = mx64(k0, k1), l0 = mn64(k0, k1);
    u64 h1 = mx64(k2, k3), l1 = mn64(k2, k3);
    u64 m0 = mx64(h0, l1), m1 = mx64(l0, h1);
    o0 = mx64(m0, m1); o1 = mn64(m0, m1);
}

// Full asc sort of 4 keys (smallest). 10 ops (2+2 merge network).
__device__ __forceinline__ void sort4_sm(f32x4 f, u32 bse,
                                         u64& b0, u64& b1, u64& b2, u64& b3) {
    u64 k0 = keysm(f.x, bse), k1 = keysm(f.y, bse + 1);
    u64 k2 = keysm(f.z, bse + 2), k3 = keysm(f.w, bse + 3);
    u64 p0 = mn64(k0, k1), p1 = mx64(k0, k1);
    u64 q0 = mn64(k2, k3), q1 = mx64(k2, k3);
    b0 = mn64(p0, q0); u64 t = mx64(p0, q0);
    b3 = mx64(p1, q1); u64 u = mn64(p1, q1);
    b1 = mn64(t, u); b2 = mx64(t, u);
}

#define NTL4(p) __builtin_nontemporal_load((const f32x4*)(p))
#define NTL2(p) __builtin_nontemporal_load((const f32x2*)(p))

// ---------------------------------------------------------------------------
// Megakernel, LPT order (longest blocks first):
//   blocks [0, 1024)     : topk0 — 4 rows/block, 512 KB each (longest)
//   blocks [1024, 1536)  : topk2 phase-1 — ~392 KB each
//   blocks [1536, 3584)  : topk1 — 4 rows/block, 64 KB each (tail filler)
// All input-stream loads are nontemporal (single-use; keep L2 for partials).
// NOTE (R9 lesson): do NOT fold the reduction in with a spin-on-atomic —
// agent-scope acquire spins cause a device-wide cache-invalidation storm
// (154 -> 264 us). Two launches with the implicit barrier are faster.
// ---------------------------------------------------------------------------
__global__ __launch_bounds__(256) void mega_kernel(
    const float* __restrict__ x0, float* __restrict__ o0v, float* __restrict__ o0i,
    const float* __restrict__ x1, float* __restrict__ o1v, float* __restrict__ o1i,
    const float* __restrict__ x2, u64* __restrict__ part, int rpb, int do_p1)
{
    const int bid  = blockIdx.x;
    const int wave = threadIdx.x >> 6;
    const int lane = threadIdx.x & 63;

    if (bid < 1024) {
        // ---- topk0: top-2 largest along rows of (4096, 32000), wave/row ----
        // 8 float4 in flight (128 B/lane); dual accumulators A/B.
        const int row = bid * 4 + wave;
        const f32x4* xr = (const f32x4*)(x0 + (size_t)row * 32000);
        u64 sA0 = 0, sA1 = 0, sB0 = 0, sB1 = 0;

        // 8000 float4/row; 125/lane = 15*8 + 5
        int v = lane;
        for (int it = 0; it < 15; ++it, v += 512) {
            f32x4 t0 = NTL4(&xr[v]);
            f32x4 t1 = NTL4(&xr[v + 64]);
            f32x4 t2 = NTL4(&xr[v + 128]);
            f32x4 t3 = NTL4(&xr[v + 192]);
            f32x4 t4 = NTL4(&xr[v + 256]);
            f32x4 t5 = NTL4(&xr[v + 320]);
            f32x4 t6 = NTL4(&xr[v + 384]);
            f32x4 t7 = NTL4(&xr[v + 448]);
            u64 w0, w1;
            top2of4_lg(t0, (u32)(v * 4),         w0, w1); merge2_lg(sA0, sA1, w0, w1);
            top2of4_lg(t1, (u32)((v + 64) * 4),  w0, w1); merge2_lg(sB0, sB1, w0, w1);
            top2of4_lg(t2, (u32)((v + 128) * 4), w0, w1); merge2_lg(sA0, sA1, w0, w1);
            top2of4_lg(t3, (u32)((v + 192) * 4), w0, w1); merge2_lg(sB0, sB1, w0, w1);
            top2of4_lg(t4, (u32)((v + 256) * 4), w0, w1); merge2_lg(sA0, sA1, w0, w1);
            top2of4_lg(t5, (u32)((v + 320) * 4), w0, w1); merge2_lg(sB0, sB1, w0, w1);
            top2of4_lg(t6, (u32)((v + 384) * 4), w0, w1); merge2_lg(sA0, sA1, w0, w1);
            top2of4_lg(t7, (u32)((v + 448) * 4), w0, w1); merge2_lg(sB0, sB1, w0, w1);
        }
        {   // tail: 5 more (v = lane + 7680; max 7999)
            f32x4 t0 = NTL4(&xr[v]);
            f32x4 t1 = NTL4(&xr[v + 64]);
            f32x4 t2 = NTL4(&xr[v + 128]);
            f32x4 t3 = NTL4(&xr[v + 192]);
            f32x4 t4 = NTL4(&xr[v + 256]);
            u64 w0, w1;
            top2of4_lg(t0, (u32)(v * 4),         w0, w1); merge2_lg(sA0, sA1, w0, w1);
            top2of4_lg(t1, (u32)((v + 64) * 4),  w0, w1); merge2_lg(sB0, sB1, w0, w1);
            top2of4_lg(t2, (u32)((v + 128) * 4), w0, w1); merge2_lg(sA0, sA1, w0, w1);
            top2of4_lg(t3, (u32)((v + 192) * 4), w0, w1); merge2_lg(sB0, sB1, w0, w1);
            top2of4_lg(t4, (u32)((v + 256) * 4), w0, w1); merge2_lg(sA0, sA1, w0, w1);
        }
        merge2_lg(sA0, sA1, sB0, sB1);

        for (int m = 1; m < 64; m <<= 1) {
            u64 b0 = shx64(sA0, m), b1 = shx64(sA1, m);
            merge2_lg(sA0, sA1, b0, b1);
        }
        if (lane == 0) {
            o0v[row * 2 + 0] = val_of(sA0);  o0v[row * 2 + 1] = val_of(sA1);
            o0i[row * 2 + 0] = idxf_lg(sA0); o0i[row * 2 + 1] = idxf_lg(sA1);
        }

    } else if (bid < 1536) {
        // ---- topk2 phase 1: column-wise top-3 over rpb rows ----
        // Thread owns 2 columns (float2); 8 rows in flight (64 B/lane).
        if (!do_p1) return;
        const int blk = bid - 1024;
        const int c0  = threadIdx.x * 2;
        int rbeg = blk * rpb;
        int rend = rbeg + rpb; if (rend > 100000) rend = 100000;

        u64 a0 = 0, a1 = 0, a2 = 0;   // col c0
        u64 b0 = 0, b1 = 0, b2 = 0;   // col c0+1

#define P1LOAD(r) NTL2(x2 + (size_t)(r) * 512 + c0)
#define P1UPD(f, rr) \
        ins3_lg(a0, a1, a2, keylg((f).x, (u32)(rr))); \
        ins3_lg(b0, b1, b2, keylg((f).y, (u32)(rr)))

        int r = rbeg;
        for (; r + 7 < rend; r += 8) {
            f32x2 f0 = P1LOAD(r);
            f32x2 f1 = P1LOAD(r + 1);
            f32x2 f2 = P1LOAD(r + 2);
            f32x2 f3 = P1LOAD(r + 3);
            f32x2 f4 = P1LOAD(r + 4);
            f32x2 f5 = P1LOAD(r + 5);
            f32x2 f6 = P1LOAD(r + 6);
            f32x2 f7 = P1LOAD(r + 7);
            P1UPD(f0, r);     P1UPD(f1, r + 1); P1UPD(f2, r + 2); P1UPD(f3, r + 3);
            P1UPD(f4, r + 4); P1UPD(f5, r + 5); P1UPD(f6, r + 6); P1UPD(f7, r + 7);
        }
        for (; r < rend; ++r) {
            f32x2 f0 = P1LOAD(r);
            P1UPD(f0, r);
        }
#undef P1LOAD
#undef P1UPD

        u64* base = part + (size_t)blk * 1536;   // [3][512]
        base[0 * 512 + c0] = a0; base[0 * 512 + c0 + 1] = b0;
        base[1 * 512 + c0] = a1; base[1 * 512 + c0 + 1] = b1;
        base[2 * 512 + c0] = a2; base[2 * 512 + c0 + 1] = b2;

    } else {
        // ---- topk1: top-4 smallest along rows of (8192, 4096), wave/row ----
        // 8 float4 in flight; sort-4 per float4 then one state merge.
        const int row = (bid - 1536) * 4 + wave;
        const f32x4* xr = (const f32x4*)(x1 + (size_t)row * 4096);
        u64 s0 = ~0ull, s1 = ~0ull, s2 = ~0ull, s3 = ~0ull;

#define K1UPD(f, b) { u64 c0_, c1_, c2_, c3_;                      \
        sort4_sm((f), (u32)(b), c0_, c1_, c2_, c3_);               \
        merge4_sm(s0, s1, s2, s3, c0_, c1_, c2_, c3_); }

        // 1024 float4/row; 16/lane = 2*8
        int v = lane;
        for (int it = 0; it < 2; ++it, v += 512) {
            f32x4 t0 = NTL4(&xr[v]);
            f32x4 t1 = NTL4(&xr[v + 64]);
            f32x4 t2 = NTL4(&xr[v + 128]);
            f32x4 t3 = NTL4(&xr[v + 192]);
            f32x4 t4 = NTL4(&xr[v + 256]);
            f32x4 t5 = NTL4(&xr[v + 320]);
            f32x4 t6 = NTL4(&xr[v + 384]);
            f32x4 t7 = NTL4(&xr[v + 448]);
            K1UPD(t0, v * 4);
            K1UPD(t1, (v + 64) * 4);
            K1UPD(t2, (v + 128) * 4);
            K1UPD(t3, (v + 192) * 4);
            K1UPD(t4, (v + 256) * 4);
            K1UPD(t5, (v + 320) * 4);
            K1UPD(t6, (v + 384) * 4);
            K1UPD(t7, (v + 448) * 4);
        }
#undef K1UPD

        for (int m = 1; m < 64; m <<= 1) {
            u64 b0 = shx64(s0, m), b1 = shx64(s1, m);
            u64 b2 = shx64(s2, m), b3 = shx64(s3, m);
            merge4_sm(s0, s1, s2, s3, b0, b1, b2, b3);
        }
        if (lane == 0) {
            o1v[row * 4 + 0] = val_of(s0);  o1v[row * 4 + 1] = val_of(s1);
            o1v[row * 4 + 2] = val_of(s2);  o1v[row * 4 + 3] = val_of(s3);
            o1i[row * 4 + 0] = idxf_sm(s0); o1i[row * 4 + 1] = idxf_sm(s1);
            o1i[row * 4 + 2] = idxf_sm(s2); o1i[row * 4 + 3] = idxf_sm(s3);
        }
    }
}

// Single-launch reduction: merge 512 partials per column + decode.
// Wave <-> column (128 blocks x 4 waves): lane l merges partials l+64j,
// then 6-step butterfly. ~6.3 MB read (L2-resident thanks to nt input loads).
__global__ __launch_bounds__(256) void topk2_reduce(
    const u64* __restrict__ part, float* __restrict__ outv, float* __restrict__ outi)
{
    const int wave = threadIdx.x >> 6;
    const int lane = threadIdx.x & 63;
    const int col  = blockIdx.x * 4 + wave;

    u64 a0 = 0, a1 = 0, a2 = 0;
#pragma unroll
    for (int j = 0; j < 8; ++j) {
        const u64* q = part + (size_t)(lane + 64 * j) * 1536 + col;
        merge3_lg(a0, a1, a2, q[0], q[512], q[1024]);
    }
    for (int m = 1; m < 64; m <<= 1) {
        u64 b0 = shx64(a0, m), b1 = shx64(a1, m), b2 = shx64(a2, m);
        merge3_lg(a0, a1, a2, b0, b1, b2);
    }

    if (lane == 0) {
        outv[0 * 512 + col] = val_of(a0);
        outv[1 * 512 + col] = val_of(a1);
        outv[2 * 512 + col] = val_of(a2);
        outi[0 * 512 + col] = idxf_lg(a0);
        outi[1 * 512 + col] = idxf_lg(a1);
        outi[2 * 512 + col] = idxf_lg(a2);
    }
}

// Fallback if workspace is too small (never expected): thread <-> column,
// coalesced row-major streaming, branchless.
__global__ __launch_bounds__(256) void topk2_direct(
    const float* __restrict__ x, float* __restrict__ outv, float* __restrict__ outi)
{
    const int col = blockIdx.x * 256 + threadIdx.x;
    u64 a0 = 0, a1 = 0, a2 = 0;
    for (int r = 0; r < 100000; ++r) {
        float v = x[(size_t)r * 512 + col];
        ins3_lg(a0, a1, a2, keylg(v, (u32)r));
    }
    outv[0 * 512 + col] = val_of(a0);
    outv[1 * 512 + col] = val_of(a1);
    outv[2 * 512 + col] = val_of(a2);
    outi[0 * 512 + col] = idxf_lg(a0);
    outi[1 * 512 + col] = idxf_lg(a1);
    outi[2 * 512 + col] = idxf_lg(a2);
}

extern "C" void kernel_launch(void* const* d_in, const int* in_sizes, int n_in,
                              void* d_out, int out_size, void* d_ws, size_t ws_size,
                              hipStream_t stream) {
    const float* v0 = (const float*)d_in[0];   // (4096, 32000)
    const float* v1 = (const float*)d_in[1];   // (8, 16, 64, 4096)
    const float* v2 = (const float*)d_in[2];   // (100000, 512)
    float* out = (float*)d_out;

    float* o_v4  = out;                 // (4096, 2) values
    float* o_v5  = out + 8192;          // (4096, 2) indices
    float* o_v7  = out + 16384;         // (8,16,64,4) values
    float* o_v8  = out + 49152;         // (8,16,64,4) indices
    float* o_v10 = out + 81920;         // (3, 512) values
    float* o_v11 = out + 83456;         // (3, 512) indices

    const int NB = 512;                           // phase-1 blocks / partials
    int rpb = (100000 + NB - 1) / NB;             // 196
    size_t need = (size_t)NB * 3 * 512 * sizeof(u64);   // ~6.3 MB

    if (ws_size >= need) {
        u64* part = (u64*)d_ws;                    // [512][3][512]
        mega_kernel<<<3584, 256, 0, stream>>>(v0, o_v4, o_v5,
                                              v1, o_v7, o_v8,
                                              v2, part, rpb, 1);
        topk2_reduce<<<128, 256, 0, stream>>>(part, o_v10, o_v11);
    } else {
        mega_kernel<<<3584, 256, 0, stream>>>(v0, o_v4, o_v5,
                                              v1, o_v7, o_v8,
                                              v2, (u64*)d_ws, rpb, 0);
        topk2_direct<<<2, 256, 0, stream>>>(v2, o_v10, o_v11);
    }
}